// Round 11
// baseline (66.552 us; speedup 1.0000x reference)
//
#include <hip/hip_runtime.h>
#include <math.h>

#define D_MODEL 2048
#define NUM_EXP 64
#define TOKB    32
#define GRAN    32               // granules of 64 k-floats (2 chunks of 32)

typedef _Float16 f16x4 __attribute__((ext_vector_type(4)));
typedef _Float16 f16x8 __attribute__((ext_vector_type(8)));
typedef float    f32x4 __attribute__((ext_vector_type(4)));

__device__ __forceinline__ void gload16(const void* g, void* l) {
    __builtin_amdgcn_global_load_lds(
        (const __attribute__((address_space(1))) unsigned int*)g,
        (__attribute__((address_space(3))) unsigned int*)l, 16, 0, 0);
}

// ---------------------------------------------------------------------------
// k0: W[64][2048] fp32 -> fragment-linear f16 hi/lo (W = wh + wl*2^-12, wl
// scaled 4096; exact). Frag (kc, mf): lane l holds
// A[m = mf*16 + (l&15)][k = kc*32 + (l>>4)*8 + j], flat at whf[(kc*4+mf)*64+l].
// ---------------------------------------------------------------------------
__global__ __launch_bounds__(256)
void k0_convw(const float* __restrict__ W, f16x8* __restrict__ whf,
              f16x8* __restrict__ wlf) {
    const int t    = blockIdx.x * 256 + threadIdx.x;
    const int lane = t & 63;
    const int mf   = (t >> 6) & 3;
    const int kc   = t >> 8;
    const int m    = mf * 16 + (lane & 15);
    const int k0   = kc * 32 + ((lane >> 4) << 3);
    const float* src = W + (size_t)m * D_MODEL + k0;
    f16x8 h, l;
#pragma unroll
    for (int j = 0; j < 8; ++j) {
        float v = src[j];
        _Float16 hh = (_Float16)v;
        h[j] = hh;
        l[j] = (_Float16)((v - (float)hh) * 4096.f);
    }
    whf[t] = h;
    wlf[t] = l;
}

// ---------------------------------------------------------------------------
// k1: counted-vmcnt pipelined fused router (T3/T4 recipe, raw barriers).
// Block = 512 thr (8 waves) = 32 tok x 64 exp x full K. Wave (tf=w&1, mf=w>>1)
// owns a 16x16 output frag, acc = ONE f32x4 pair, full-K accumulate.
// Per granule g (64 k): issue x(g+1) reg-load, then W(g+2) via global_load_lds
// (f16 frag-linear source, linear LDS dest, triple-buffered); compute granule
// g (2 chunks x 3 MFMA of the exact split logits = xh*wh + 2^-12(xh*wl+xl*wh));
// s_waitcnt vmcnt(2)  [FIFO retires W(g+1)pair + x(g+1), leaves W(g+2) pair
// in flight -- never drains]; SWRITE x(g+1) (cvt once -> swizzled f16 LDS);
// lgkmcnt(0); raw s_barrier. NO __syncthreads in the loop (it would emit
// vmcnt(0) and kill the pipeline). W-tail issues wrap (&31) so counts stay
// uniform; their buffer index follows issue position (g+2)%3 -- no clash.
// x LDS swizzle: piece p (16B) of row r stored at p^(r&7) -> frag reads 2-way.
// Epilogue: ep tile -> per-wave softmax + top-2 (lax.top_k tie rule: lower
// index wins) + per-block expert partials. All sums fixed-order.
// LDS 74 KB -> 2 blocks/CU (512 blocks / 256 CU), 4 waves/SIMD.
// ---------------------------------------------------------------------------
__global__ __launch_bounds__(512, 4)
void k1_fused(const float* __restrict__ x, const f16x8* __restrict__ whf,
              const f16x8* __restrict__ wlf, float* __restrict__ out,
              float* __restrict__ p_part, float* __restrict__ f_part, int N) {
    const int tid  = threadIdx.x;
    const int lane = tid & 63;
    const int w    = tid >> 6;          // 0..7
    const int tf   = w & 1;
    const int mf   = w >> 1;            // 0..3
    const int tok0 = blockIdx.x * TOKB;

    __shared__ _Float16 xh_s[2][TOKB][64];   // 8 KB
    __shared__ _Float16 xl_s[2][TOKB][64];   // 8 KB
    __shared__ f16x8    w_s[3][16][64];      // 48 KB [buf][slot][lane]
    __shared__ float    ep[TOKB][NUM_EXP];   // 8 KB
    __shared__ float    p_red[8][64], f_red[8][64];

    // x stage map: thread t -> row = t>>4 (32 rows), col4 = t&15 (16 float4 =
    // 64 floats per granule-row). Swizzled f16 dest: piece p = col4>>1,
    // half = col4&1, byte = ((p ^ (row&7))<<4) + (half<<3).
    const int srow = tid >> 4;
    const int sc4  = tid & 15;
    const float* xsrc = x + (size_t)(tok0 + srow) * D_MODEL + sc4 * 4;
    const int    xko  = (((sc4 >> 1) ^ (srow & 7)) << 4) + ((sc4 & 1) << 3);

    // W stage map: wave w stages (cs = w>>2 chunk-in-granule, mfs = w&3),
    // both hi (slot base) and lo (slot base+1). slot = cs*8 + mfs*2 + h.
    const int cs = w >> 2, mfs = w & 3;
    const int wslot = cs * 8 + mfs * 2;
    const f16x8* whsrc = whf + (cs * 4 + mfs) * 64 + lane;   // + gsrc*512
    const f16x8* wlsrc = wlf + (cs * 4 + mfs) * 64 + lane;

    f32x4 acc1 = f32x4{0.f, 0.f, 0.f, 0.f};
    f32x4 acc2 = f32x4{0.f, 0.f, 0.f, 0.f};

    const int ft = lane & 15;
    const int fs = lane >> 4;
    const int r7 = lane & 7;            // (tf*16 + ft) & 7 == lane & 7

    auto WISSUE = [&](int gbuf, int gsrc) {
        gload16(whsrc + (size_t)gsrc * 512, &w_s[gbuf][wslot][0]);
        gload16(wlsrc + (size_t)gsrc * 512, &w_s[gbuf][wslot + 1][0]);
    };
    auto SWRITE = [&](int b, float4 v) {
        const float vf[4] = {v.x, v.y, v.z, v.w};
        f16x4 h, l;
#pragma unroll
        for (int j = 0; j < 4; ++j) {
            _Float16 hh = (_Float16)vf[j];
            h[j] = hh;
            l[j] = (_Float16)((vf[j] - (float)hh) * 4096.f);
        }
        *(f16x4*)((char*)&xh_s[b][srow][0] + xko) = h;
        *(f16x4*)((char*)&xl_s[b][srow][0] + xko) = l;
    };
    auto COMPUTE = [&](int b, int wb) {
        const char* xhb = (const char*)&xh_s[b][tf * 16 + ft][0];
        const char* xlb = (const char*)&xl_s[b][tf * 16 + ft][0];
#pragma unroll
        for (int c = 0; c < 2; ++c) {
            const int off = ((c * 4 + fs) ^ r7) << 4;
            const f16x8 xh = *(const f16x8*)(xhb + off);
            const f16x8 xl = *(const f16x8*)(xlb + off);
            const f16x8 wh = w_s[wb][c * 8 + mf * 2 + 0][lane];
            const f16x8 wl = w_s[wb][c * 8 + mf * 2 + 1][lane];
            acc1 = __builtin_amdgcn_mfma_f32_16x16x32_f16(wh, xh, acc1, 0, 0, 0);
            acc2 = __builtin_amdgcn_mfma_f32_16x16x32_f16(wh, xl, acc2, 0, 0, 0);
            acc2 = __builtin_amdgcn_mfma_f32_16x16x32_f16(wl, xh, acc2, 0, 0, 0);
        }
    };

    // --- prologue: queue [x0, W0h, W0l, W1h, W1l]; vmcnt(2) retires x0+W0 ---
    {
        float4 xv = *(const float4*)(xsrc);
        __builtin_amdgcn_sched_barrier(0);
        WISSUE(0, 0);
        WISSUE(1, 1);
        asm volatile("s_waitcnt vmcnt(2)" ::: "memory");
        __builtin_amdgcn_sched_barrier(0);
        SWRITE(0, xv);
        asm volatile("s_waitcnt lgkmcnt(0)" ::: "memory");
        __builtin_amdgcn_s_barrier();
    }

    // --- main loop: steady queue depth 5, vmcnt never drained to 0 ---------
#pragma unroll
    for (int g = 0; g < GRAN; ++g) {
        float4 xn = *(const float4*)(xsrc + (size_t)((g + 1) & 31) * 64);
        __builtin_amdgcn_sched_barrier(0);
        WISSUE((g + 2) % 3, (g + 2) & 31);
        __builtin_amdgcn_sched_barrier(0);
        COMPUTE(g & 1, g % 3);
        asm volatile("s_waitcnt vmcnt(2)" ::: "memory");
        __builtin_amdgcn_sched_barrier(0);
        SWRITE((g + 1) & 1, xn);
        asm volatile("s_waitcnt lgkmcnt(0)" ::: "memory");
        __builtin_amdgcn_s_barrier();
    }

    // --- epilogue: logits tile (C: col = lane&15 = token, row = fs*4+p) ----
    {
        f32x4 o = acc1 + acc2 * (1.f / 4096.f);
        *(f32x4*)&ep[tf * 16 + ft][mf * 16 + fs * 4] = o;
    }
    __syncthreads();

    // --- softmax + top-2, 4 tokens per wave (lane == expert) ---------------
    float pacc = 0.f, facc = 0.f;
#pragma unroll
    for (int i = 0; i < 4; ++i) {
        const int tl = w * 4 + i;
        float logit = ep[tl][lane];

        float m = logit;
        for (int off = 32; off; off >>= 1) m = fmaxf(m, __shfl_xor(m, off));
        float p = __expf(logit - m);
        float S = p;
        for (int off = 32; off; off >>= 1) S += __shfl_xor(S, off);
        float prob = p / S;

        float bv = logit; int bi = lane;
        for (int off = 32; off; off >>= 1) {
            float ov = __shfl_xor(bv, off);
            int   oi = __shfl_xor(bi, off);
            if (ov > bv || (ov == bv && oi < bi)) { bv = ov; bi = oi; }
        }
        float cv = (lane == bi) ? -INFINITY : logit;
        int   ci = lane;
        for (int off = 32; off; off >>= 1) {
            float ov = __shfl_xor(cv, off);
            int   oi = __shfl_xor(ci, off);
            if (ov > cv || (ov == cv && oi < ci)) { cv = ov; ci = oi; }
        }

        if (lane == 0) {
            const int gt = tok0 + tl;
            float w0 = 1.f / (1.f + __expf(cv - bv));
            out[(size_t)gt * 2]     = w0;
            out[(size_t)gt * 2 + 1] = 1.f - w0;
            out[(size_t)2 * N + gt * 2]     = (float)bi;
            out[(size_t)2 * N + gt * 2 + 1] = (float)ci;
        }

        pacc += prob;
        facc += (lane == bi ? 1.f : 0.f) + (lane == ci ? 1.f : 0.f);
    }

    p_red[w][lane] = pacc;
    f_red[w][lane] = facc;
    __syncthreads();
    if (w == 0) {
        float sp = 0.f, sf = 0.f;
#pragma unroll
        for (int q = 0; q < 8; ++q) { sp += p_red[q][lane]; sf += f_red[q][lane]; }
        p_part[(size_t)blockIdx.x * NUM_EXP + lane] = sp;
        f_part[(size_t)blockIdx.x * NUM_EXP + lane] = sf;
    }
}

// ---------------------------------------------------------------------------
// k3: deterministic aux-loss reduction over 512 per-block partials.
// aux = E * sum_i (f_sum_i / N) * (p_sum_i / N)
// ---------------------------------------------------------------------------
__global__ __launch_bounds__(1024)
void k3_aux(const float* __restrict__ p_part, const float* __restrict__ f_part,
            float* __restrict__ out, int N, int B2) {
    const int lane = threadIdx.x & 63;
    const int wid  = threadIdx.x >> 6;    // 0..15
    float sp = 0.f, sf = 0.f;
    for (int b = wid; b < B2; b += 16) {
        sp += p_part[(size_t)b * NUM_EXP + lane];
        sf += f_part[(size_t)b * NUM_EXP + lane];
    }
    __shared__ float lsp[16][64];
    __shared__ float lsf[16][64];
    lsp[wid][lane] = sp;
    lsf[wid][lane] = sf;
    __syncthreads();
    if (wid == 0) {
        float tsp = 0.f, tsf = 0.f;
#pragma unroll
        for (int q = 0; q < 16; ++q) { tsp += lsp[q][lane]; tsf += lsf[q][lane]; }
        float v = tsp * tsf;
        for (int off = 32; off; off >>= 1) v += __shfl_xor(v, off);
        if (lane == 0)
            out[(size_t)4 * N] = (float)NUM_EXP * v / ((float)N * (float)N);
    }
}

extern "C" void kernel_launch(void* const* d_in, const int* in_sizes, int n_in,
                              void* d_out, int out_size, void* d_ws, size_t ws_size,
                              hipStream_t stream) {
    const float* x = (const float*)d_in[0];
    const float* W = (const float*)d_in[1];
    float* out = (float*)d_out;

    const int N  = in_sizes[0] / D_MODEL;   // 16384
    const int B1 = N / TOKB;                // 512 blocks

    // ws: [whf 256KB][wlf 256KB][p_part 128KB][f_part 128KB]
    f16x8* whf = (f16x8*)d_ws;
    f16x8* wlf = whf + 16384;
    float* p_part = (float*)(wlf + 16384);
    float* f_part = p_part + (size_t)B1 * NUM_EXP;

    k0_convw<<<64, 256, 0, stream>>>(W, whf, wlf);
    k1_fused<<<B1, 512, 0, stream>>>(x, whf, wlf, out, p_part, f_part, N);
    k3_aux<<<1, 1024, 0, stream>>>(p_part, f_part, out, N, B1);
}